// Round 6
// baseline (1836.852 us; speedup 1.0000x reference)
//
#include <hip/hip_runtime.h>

// ---------------------------------------------------------------------------
// Swin block, round 5: (1) GEMM staging via global_load_lds width=16 with
// linear LDS tiles (m97 pattern); (2) attention Q/K pad 4->8 (stride 40
// words: 8-way -> 4-way bank conflict on QK^T ds_read_b128).
// Pipeline unchanged:
//  T   transpose+cvt weights  w_*          -> wT (bf16 [N][K])
//  K1  ln1+shift+window       x            -> buf1 (bf16, windowed TOKx384)
//  K2  qkv mfma gemm (x4)     buf1 chunk   -> buf4 (fp32 chunk x 1152)
//  K3  attention (x4)         buf4         -> buf2 (bf16 ctx, windowed)
//  K4  proj mfma gemm         buf2         -> buf3 (fp32, windowed)
//  K5  unshift+residual+LN2   x, buf3      -> d_out (h fp32), buf1 (ln2 bf16)
//  K6  fc1 mfma gemm+GELU(x4) buf1 chunk   -> buf4 (bf16 chunk x 1536)
//  K7  fc2 mfma gemm+res (x4) buf4, d_out  -> d_out
// ---------------------------------------------------------------------------

#define DIMC   384
#define HEADS  12
#define HDIM   32
#define WSZ    7
#define SHIFTS 3
#define NTOK   49
#define HID    1536
#define BATCH  32
#define HH     56
#define WW2    56
#define NW     64
#define NWIN   (BATCH*NW)   // 2048
#define TOK    (NWIN*NTOK)  // 100352
#define QKSCALE 0.17677669529663687f

#define NCHUNK 4
#define ROWS_PER_CHUNK (TOK/NCHUNK)     // 25088
#define WIN_PER_CHUNK  (NWIN/NCHUNK)    // 512

typedef short bf16x8 __attribute__((ext_vector_type(8)));
typedef float f32x4 __attribute__((ext_vector_type(4)));

__device__ __forceinline__ unsigned short f2bf(float f) {
  unsigned int u = __builtin_bit_cast(unsigned int, f);
  u += 0x7fffu + ((u >> 16) & 1u);
  return (unsigned short)(u >> 16);
}

// async global->LDS, 16B per lane. LDS dest = wave-uniform base + lane*16.
__device__ __forceinline__ void gload_lds16(const unsigned short* g,
                                            unsigned short* lds_base_uniform) {
  __builtin_amdgcn_global_load_lds(
      (const __attribute__((address_space(1))) void*)g,
      (__attribute__((address_space(3))) void*)lds_base_uniform, 16, 0, 0);
}

__device__ __forceinline__ float wave_sum(float v) {
#pragma unroll
  for (int o = 32; o > 0; o >>= 1) v += __shfl_xor(v, o, 64);
  return v;
}
__device__ __forceinline__ float wave_max(float v) {
#pragma unroll
  for (int o = 32; o > 0; o >>= 1) v = fmaxf(v, __shfl_xor(v, o, 64));
  return v;
}

// --------------------------- weight transpose + bf16 cvt -------------------
__global__ __launch_bounds__(256) void transpose_cvt_kernel(
    const float* __restrict__ W, unsigned short* __restrict__ Wt, int K, int N) {
  __shared__ float t[32][33];
  int k0 = blockIdx.x * 32, n0 = blockIdx.y * 32;
  int tx = threadIdx.x & 31, ty = threadIdx.x >> 5;
#pragma unroll
  for (int i = 0; i < 4; i++) {
    int k = ty + i * 8;
    t[k][tx] = W[(size_t)(k0 + k) * N + n0 + tx];
  }
  __syncthreads();
#pragma unroll
  for (int i = 0; i < 4; i++) {
    int n = ty + i * 8;
    Wt[(size_t)(n0 + n) * K + k0 + tx] = f2bf(t[tx][n]);
  }
}

// --------------------------- K1: LN1 + shift + window ----------------------
__global__ __launch_bounds__(256) void ln1_window_kernel(
    const float* __restrict__ x, const float* __restrict__ gamma,
    const float* __restrict__ beta, unsigned short* __restrict__ out) {
  int wave = threadIdx.x >> 6, lane = threadIdx.x & 63;
  int token = blockIdx.x * 4 + wave;
  if (token >= TOK) return;
  int n  = token % NTOK;
  int b_ = token / NTOK;
  int b  = b_ >> 6;
  int w  = b_ & 63;
  int yw = (w >> 3) * WSZ + n / WSZ;
  int xw = (w & 7) * WSZ + n % WSZ;
  int ys = yw + SHIFTS; if (ys >= HH)  ys -= HH;
  int xs = xw + SHIFTS; if (xs >= WW2) xs -= WW2;
  const float* src = x + (size_t)(b * HH * WW2 + ys * WW2 + xs) * DIMC;
  float v[6], s = 0.f, s2 = 0.f;
#pragma unroll
  for (int i = 0; i < 6; i++) {
    v[i] = src[lane + 64 * i];
    s += v[i]; s2 += v[i] * v[i];
  }
  s = wave_sum(s); s2 = wave_sum(s2);
  float mu = s * (1.f / DIMC);
  float var = s2 * (1.f / DIMC) - mu * mu;
  float r = rsqrtf(var + 1e-5f);
  unsigned short* dst = out + (size_t)token * DIMC;
#pragma unroll
  for (int i = 0; i < 6; i++) {
    int c = lane + 64 * i;
    dst[c] = f2bf((v[i] - mu) * r * gamma[c] + beta[c]);
  }
}

// --------------------------- bf16 MFMA GEMM --------------------------------
// C[M,N] = act(A[M,K]bf16 @ Bt[N,K]bf16^T + bias) (+addsrc). 128x128 tile,
// BK=64, 256 threads (4 waves, 2x2 of 64x64), 4x4 16x16x32 frags per wave.
// Staging: global_load_lds dwordx4, linear LDS [128][64] (no pad — the
// wave-uniform-base+lane*16 dest requires it).
template <bool GELU_ACT, bool ADD_SRC, bool OUT_BF16>
__global__ __launch_bounds__(256) void gemm_bf16_kernel(
    const unsigned short* __restrict__ A, const unsigned short* __restrict__ Bt,
    const float* __restrict__ bias, const float* __restrict__ addsrc,
    void* __restrict__ C, int M, int N, int K) {
  __shared__ unsigned short As[128][64];
  __shared__ unsigned short Bs[128][64];
  int tid = threadIdx.x;
  int lane = tid & 63, wid = tid >> 6;
  int wm = wid >> 1, wn = wid & 1;
  int bm0 = blockIdx.x * 128, bn0 = blockIdx.y * 128;

  f32x4 acc[4][4];
#pragma unroll
  for (int m = 0; m < 4; m++)
#pragma unroll
    for (int n = 0; n < 4; n++) acc[m][n] = (f32x4){0.f, 0.f, 0.f, 0.f};

  const unsigned short* Ab = A + (size_t)bm0 * K;
  const unsigned short* Bb = Bt + (size_t)bn0 * K;
  unsigned short* Asf = &As[0][0];
  unsigned short* Bsf = &Bs[0][0];

  for (int k0 = 0; k0 < K; k0 += 64) {
    // stage 128x64 bf16 per matrix: 1024 slots of 16B; wave w, iter it
    // covers slots [it*256 + w*64, +64): LDS linear = slot*16B.
#pragma unroll
    for (int it = 0; it < 4; it++) {
      int idx = it * 256 + wid * 64 + lane;       // per-lane slot
      int row = idx >> 3, seg = idx & 7;
      unsigned short* lbase = Asf + (size_t)(it * 256 + wid * 64) * 8;  // uniform
      gload_lds16(Ab + (size_t)row * K + k0 + seg * 8, lbase);
      unsigned short* lbase2 = Bsf + (size_t)(it * 256 + wid * 64) * 8;
      gload_lds16(Bb + (size_t)row * K + k0 + seg * 8, lbase2);
    }
    __syncthreads();
#pragma unroll
    for (int kk = 0; kk < 2; kk++) {
      bf16x8 af[4], bfr[4];
      int kof = kk * 32 + (lane >> 4) * 8;
#pragma unroll
      for (int m = 0; m < 4; m++)
        af[m] = *(const bf16x8*)&As[wm * 64 + m * 16 + (lane & 15)][kof];
#pragma unroll
      for (int n = 0; n < 4; n++)
        bfr[n] = *(const bf16x8*)&Bs[wn * 64 + n * 16 + (lane & 15)][kof];
#pragma unroll
      for (int m = 0; m < 4; m++)
#pragma unroll
        for (int n = 0; n < 4; n++)
          acc[m][n] = __builtin_amdgcn_mfma_f32_16x16x32_bf16(
              af[m], bfr[n], acc[m][n], 0, 0, 0);
    }
    __syncthreads();
  }

  // epilogue: C/D layout col = lane&15, row = (lane>>4)*4 + i
#pragma unroll
  for (int n = 0; n < 4; n++) {
    int col = bn0 + wn * 64 + n * 16 + (lane & 15);
    float bb = bias[col];
#pragma unroll
    for (int m = 0; m < 4; m++) {
      int rowb = bm0 + wm * 64 + m * 16 + ((lane >> 4) << 2);
#pragma unroll
      for (int i = 0; i < 4; i++) {
        float v = acc[m][n][i] + bb;
        if (GELU_ACT) v = 0.5f * v * (1.f + erff(v * 0.70710678118f));
        size_t off = (size_t)(rowb + i) * N + col;
        if (ADD_SRC) v += addsrc[off];
        if (OUT_BF16) ((unsigned short*)C)[off] = f2bf(v);
        else          ((float*)C)[off] = v;
      }
    }
  }
}

// --------------------------- K3: windowed attention ------------------------
// Q/K/V rows padded to 40 floats (stride 40 words: bank = 8j mod 32 ->
// 4-way conflict on K[j] float4 reads, down from 8-way at stride 36).
__device__ __forceinline__ int regid(int y) { return y < 49 ? 0 : (y < 53 ? 1 : 2); }

__global__ __launch_bounds__(256) void attn_kernel(
    const float* __restrict__ qkv, const float* __restrict__ rel_table,
    unsigned short* __restrict__ ctx, int wbase) {
  __shared__ float Q[NTOK][HDIM + 8];
  __shared__ float Km[NTOK][HDIM + 8];
  __shared__ float Vm[NTOK][HDIM + 8];
  __shared__ float S[NTOK][NTOK + 1];
  __shared__ float rel_s[169];
  __shared__ int rid[NTOK];

  int bwl = blockIdx.x / HEADS;
  int h   = blockIdx.x % HEADS;
  int bwg = wbase + bwl;
  int tid = threadIdx.x;

  const float* base = qkv + (size_t)bwl * NTOK * (3 * DIMC) + h * HDIM;
  for (int idx = tid; idx < NTOK * HDIM; idx += 256) {
    int n = idx >> 5, d = idx & 31;
    const float* rowp = base + (size_t)n * (3 * DIMC);
    Q[n][d]  = rowp[d] * QKSCALE;
    Km[n][d] = rowp[DIMC + d];
    Vm[n][d] = rowp[2 * DIMC + d];
  }
  for (int idx = tid; idx < 169; idx += 256) rel_s[idx] = rel_table[idx * HEADS + h];
  {
    int w = bwg & 63, wy = w >> 3, wx = w & 7;
    for (int idx = tid; idx < NTOK; idx += 256)
      rid[idx] = regid(wy * WSZ + idx / WSZ) * 3 + regid(wx * WSZ + idx % WSZ);
  }
  __syncthreads();

  for (int idx = tid; idx < NTOK * NTOK; idx += 256) {
    int i = idx / NTOK, j = idx % NTOK;
    float s = 0.f;
#pragma unroll
    for (int d4 = 0; d4 < 8; d4++) {
      float4 qa = *(const float4*)&Q[i][d4 * 4];
      float4 kb = *(const float4*)&Km[j][d4 * 4];
      s += qa.x * kb.x + qa.y * kb.y + qa.z * kb.z + qa.w * kb.w;
    }
    int yi = i / WSZ, xi = i % WSZ, yj = j / WSZ, xj = j % WSZ;
    s += rel_s[(yi - yj + 6) * 13 + (xi - xj + 6)];
    if (rid[i] != rid[j]) s -= 100.f;
    S[i][j] = s;
  }
  __syncthreads();

  int wave = tid >> 6, lane = tid & 63;
  for (int r = wave; r < NTOK; r += 4) {
    float vv = (lane < NTOK) ? S[r][lane] : -1e30f;
    float m = wave_max(vv);
    float e = (lane < NTOK) ? __expf(vv - m) : 0.f;
    float ssum = wave_sum(e);
    if (lane < NTOK) S[r][lane] = e * (1.f / ssum);
  }
  __syncthreads();

  for (int idx = tid; idx < NTOK * (HDIM / 4); idx += 256) {
    int i = idx >> 3, d4 = idx & 7;
    float4 o = {0.f, 0.f, 0.f, 0.f};
#pragma unroll 7
    for (int j = 0; j < NTOK; j++) {
      float p = S[i][j];
      float4 vv = *(const float4*)&Vm[j][d4 * 4];
      o.x += p * vv.x; o.y += p * vv.y; o.z += p * vv.z; o.w += p * vv.w;
    }
    ushort4 o4 = {f2bf(o.x), f2bf(o.y), f2bf(o.z), f2bf(o.w)};
    *(ushort4*)&ctx[((size_t)bwg * NTOK + i) * DIMC + h * HDIM + d4 * 4] = o4;
  }
}

// --------------------------- K5: unshift + residual + LN2 ------------------
__global__ __launch_bounds__(256) void unshift_ln2_kernel(
    const float* __restrict__ x, const float* __restrict__ projw,
    const float* __restrict__ gamma, const float* __restrict__ beta,
    float* __restrict__ hout, unsigned short* __restrict__ ln2) {
  int wave = threadIdx.x >> 6, lane = threadIdx.x & 63;
  int token = blockIdx.x * 4 + wave;
  if (token >= TOK) return;
  int b = token / (HH * WW2);
  int yx = token % (HH * WW2);
  int y = yx / WW2, xq = yx % WW2;
  int ys = y - SHIFTS;  if (ys < 0) ys += HH;
  int xs = xq - SHIFTS; if (xs < 0) xs += WW2;
  int wtok = (b * NW + (ys / WSZ) * 8 + (xs / WSZ)) * NTOK + (ys % WSZ) * WSZ + (xs % WSZ);
  const float* xp = x + (size_t)token * DIMC;
  const float* pp = projw + (size_t)wtok * DIMC;
  float v[6], s = 0.f, s2 = 0.f;
#pragma unroll
  for (int i = 0; i < 6; i++) {
    int c = lane + 64 * i;
    float hv = xp[c] + pp[c];
    v[i] = hv; s += hv; s2 += hv * hv;
  }
  s = wave_sum(s); s2 = wave_sum(s2);
  float mu = s * (1.f / DIMC);
  float var = s2 * (1.f / DIMC) - mu * mu;
  float r = rsqrtf(var + 1e-5f);
  float* hp = hout + (size_t)token * DIMC;
  unsigned short* lp = ln2 + (size_t)token * DIMC;
#pragma unroll
  for (int i = 0; i < 6; i++) {
    int c = lane + 64 * i;
    hp[c] = v[i];
    lp[c] = f2bf((v[i] - mu) * r * gamma[c] + beta[c]);
  }
}

// --------------------------- launch ----------------------------------------
extern "C" void kernel_launch(void* const* d_in, const int* in_sizes, int n_in,
                              void* d_out, int out_size, void* d_ws, size_t ws_size,
                              hipStream_t stream) {
  const float* x      = (const float*)d_in[0];
  const float* gamma1 = (const float*)d_in[1];
  const float* beta1  = (const float*)d_in[2];
  const float* w_qkv  = (const float*)d_in[3];
  const float* b_qkv  = (const float*)d_in[4];
  const float* rel_t  = (const float*)d_in[5];
  const float* w_proj = (const float*)d_in[6];
  const float* b_proj = (const float*)d_in[7];
  const float* gamma2 = (const float*)d_in[8];
  const float* beta2  = (const float*)d_in[9];
  const float* w_fc1  = (const float*)d_in[10];
  const float* b_fc1  = (const float*)d_in[11];
  const float* w_fc2  = (const float*)d_in[12];
  const float* b_fc2  = (const float*)d_in[13];

  char* p = (char*)d_ws;
  unsigned short* wqkvT = (unsigned short*)p; p += (size_t)1152 * 384 * 2;
  unsigned short* wprojT = (unsigned short*)p; p += (size_t)384 * 384 * 2;
  unsigned short* wfc1T = (unsigned short*)p; p += (size_t)1536 * 384 * 2;
  unsigned short* wfc2T = (unsigned short*)p; p += (size_t)384 * 1536 * 2;
  unsigned short* buf1 = (unsigned short*)p; p += (size_t)TOK * DIMC * 2;
  unsigned short* buf2 = (unsigned short*)p; p += (size_t)TOK * DIMC * 2;
  float* buf3 = (float*)p; p += (size_t)TOK * DIMC * 4;
  float* buf4 = (float*)p;  // chunk scratch: max(25088*1152 f32, 25088*1536 bf16)
  float* out = (float*)d_out;

  // weight transpose + cvt
  transpose_cvt_kernel<<<dim3(384 / 32, 1152 / 32), 256, 0, stream>>>(w_qkv, wqkvT, 384, 1152);
  transpose_cvt_kernel<<<dim3(384 / 32, 384 / 32), 256, 0, stream>>>(w_proj, wprojT, 384, 384);
  transpose_cvt_kernel<<<dim3(384 / 32, 1536 / 32), 256, 0, stream>>>(w_fc1, wfc1T, 384, 1536);
  transpose_cvt_kernel<<<dim3(1536 / 32, 384 / 32), 256, 0, stream>>>(w_fc2, wfc2T, 1536, 384);

  // K1
  ln1_window_kernel<<<TOK / 4, 256, 0, stream>>>(x, gamma1, beta1, buf1);

  // K2/K3 chunked
  for (int c = 0; c < NCHUNK; c++) {
    const unsigned short* in = buf1 + (size_t)c * ROWS_PER_CHUNK * DIMC;
    gemm_bf16_kernel<false, false, false>
        <<<dim3(ROWS_PER_CHUNK / 128, 1152 / 128), 256, 0, stream>>>(
        in, wqkvT, b_qkv, nullptr, buf4, ROWS_PER_CHUNK, 3 * DIMC, DIMC);
    attn_kernel<<<WIN_PER_CHUNK * HEADS, 256, 0, stream>>>(
        buf4, rel_t, buf2, c * WIN_PER_CHUNK);
  }

  // K4: proj
  gemm_bf16_kernel<false, false, false>
      <<<dim3(TOK / 128, DIMC / 128), 256, 0, stream>>>(
      buf2, wprojT, b_proj, nullptr, buf3, TOK, DIMC, DIMC);

  // K5
  unshift_ln2_kernel<<<TOK / 4, 256, 0, stream>>>(x, buf3, gamma2, beta2, out, buf1);

  // K6/K7 chunked MLP
  for (int c = 0; c < NCHUNK; c++) {
    const unsigned short* in = buf1 + (size_t)c * ROWS_PER_CHUNK * DIMC;
    float* hrow = out + (size_t)c * ROWS_PER_CHUNK * DIMC;
    gemm_bf16_kernel<true, false, true>
        <<<dim3(ROWS_PER_CHUNK / 128, HID / 128), 256, 0, stream>>>(
        in, wfc1T, b_fc1, nullptr, buf4, ROWS_PER_CHUNK, HID, DIMC);
    gemm_bf16_kernel<false, true, false>
        <<<dim3(ROWS_PER_CHUNK / 128, DIMC / 128), 256, 0, stream>>>(
        (const unsigned short*)buf4, wfc2T, b_fc2, hrow, hrow, ROWS_PER_CHUNK, DIMC, HID);
  }
}

// Round 7
// 1326.189 us; speedup vs baseline: 1.3851x; 1.3851x over previous
//
#include <hip/hip_runtime.h>

// ---------------------------------------------------------------------------
// Swin block, round 7: MFMA attention (wave-per-(window,head), swapped QK^T,
// precomputed bias+mask table, swizzled P/V^T in LDS). GEMM staging reverted
// to round-5 reg-staged+pad72 (measured faster than gload_lds at these K).
// qkv + proj GEMM outputs now bf16.
//  T    transpose+cvt weights
//  B    bias+mask precompute    rel_table   -> combined[4][12][64][64] f32
//  K1   ln1+shift+window        x           -> buf1 (bf16 windowed)
//  K2   qkv gemm (x4, bf16 out) buf1 chunk  -> buf4 (bf16 chunk x 1152)
//  K3   attn mfma (x4)          buf4        -> buf2 (bf16 ctx)
//  K4   proj gemm (bf16 out)    buf2        -> buf3 (bf16)
//  K5   unshift+res+LN2         x, buf3     -> d_out (f32), buf1 (bf16)
//  K6   fc1 gemm+GELU (x4)      buf1 chunk  -> buf4 (bf16 chunk x 1536)
//  K7   fc2 gemm+res (x4)       buf4, d_out -> d_out
// ---------------------------------------------------------------------------

#define DIMC   384
#define HEADS  12
#define HDIM   32
#define WSZ    7
#define SHIFTS 3
#define NTOK   49
#define HID    1536
#define BATCH  32
#define HH     56
#define WW2    56
#define NW     64
#define NWIN   (BATCH*NW)   // 2048
#define TOK    (NWIN*NTOK)  // 100352
#define QKSCALE 0.17677669529663687f

#define NCHUNK 4
#define ROWS_PER_CHUNK (TOK/NCHUNK)     // 25088
#define WIN_PER_CHUNK  (NWIN/NCHUNK)    // 512

typedef short bf16x8 __attribute__((ext_vector_type(8)));
typedef float f32x4 __attribute__((ext_vector_type(4)));
typedef unsigned short ushort8_t __attribute__((ext_vector_type(8)));

__device__ __forceinline__ unsigned short f2bf(float f) {
  unsigned int u = __builtin_bit_cast(unsigned int, f);
  u += 0x7fffu + ((u >> 16) & 1u);
  return (unsigned short)(u >> 16);
}
__device__ __forceinline__ float bf2f(unsigned short s) {
  unsigned int u = ((unsigned int)s) << 16;
  return __builtin_bit_cast(float, u);
}

__device__ __forceinline__ float wave_sum(float v) {
#pragma unroll
  for (int o = 32; o > 0; o >>= 1) v += __shfl_xor(v, o, 64);
  return v;
}

// --------------------------- weight transpose + bf16 cvt -------------------
__global__ __launch_bounds__(256) void transpose_cvt_kernel(
    const float* __restrict__ W, unsigned short* __restrict__ Wt, int K, int N) {
  __shared__ float t[32][33];
  int k0 = blockIdx.x * 32, n0 = blockIdx.y * 32;
  int tx = threadIdx.x & 31, ty = threadIdx.x >> 5;
#pragma unroll
  for (int i = 0; i < 4; i++) {
    int k = ty + i * 8;
    t[k][tx] = W[(size_t)(k0 + k) * N + n0 + tx];
  }
  __syncthreads();
#pragma unroll
  for (int i = 0; i < 4; i++) {
    int n = ty + i * 8;
    Wt[(size_t)(n0 + n) * K + k0 + tx] = f2bf(t[tx][n]);
  }
}

// --------------------------- bias+mask precompute --------------------------
// combined[cls][h][qt][kt], cls = (wy==7)<<1 | (wx==7).
__global__ __launch_bounds__(256) void bias_precompute_kernel(
    const float* __restrict__ rel, float* __restrict__ combined) {
  int idx = blockIdx.x * 256 + threadIdx.x;      // 4*12*64*64 = 196608
  int kt = idx & 63, qt = (idx >> 6) & 63;
  int hc = idx >> 12;                            // 0..47
  int h = hc % 12, cls = hc / 12;
  float v;
  if (kt >= NTOK) v = -30000.f;
  else if (qt >= NTOK) v = 0.f;
  else {
    int yq = qt / 7, xq = qt % 7, yk = kt / 7, xk = kt % 7;
    v = rel[((yq - yk + 6) * 13 + (xq - xk + 6)) * HEADS + h];
    int wy7 = cls >> 1, wx7 = cls & 1;
    int rq = (wy7 ? (yq < 4 ? 1 : 2) : 0) * 3 + (wx7 ? (xq < 4 ? 1 : 2) : 0);
    int rk = (wy7 ? (yk < 4 ? 1 : 2) : 0) * 3 + (wx7 ? (xk < 4 ? 1 : 2) : 0);
    if (rq != rk) v -= 100.f;
  }
  combined[idx] = v;
}

// --------------------------- K1: LN1 + shift + window ----------------------
__global__ __launch_bounds__(256) void ln1_window_kernel(
    const float* __restrict__ x, const float* __restrict__ gamma,
    const float* __restrict__ beta, unsigned short* __restrict__ out) {
  int wave = threadIdx.x >> 6, lane = threadIdx.x & 63;
  int token = blockIdx.x * 4 + wave;
  if (token >= TOK) return;
  int n  = token % NTOK;
  int b_ = token / NTOK;
  int b  = b_ >> 6;
  int w  = b_ & 63;
  int yw = (w >> 3) * WSZ + n / WSZ;
  int xw = (w & 7) * WSZ + n % WSZ;
  int ys = yw + SHIFTS; if (ys >= HH)  ys -= HH;
  int xs = xw + SHIFTS; if (xs >= WW2) xs -= WW2;
  const float* src = x + (size_t)(b * HH * WW2 + ys * WW2 + xs) * DIMC;
  float v[6], s = 0.f, s2 = 0.f;
#pragma unroll
  for (int i = 0; i < 6; i++) {
    v[i] = src[lane + 64 * i];
    s += v[i]; s2 += v[i] * v[i];
  }
  s = wave_sum(s); s2 = wave_sum(s2);
  float mu = s * (1.f / DIMC);
  float var = s2 * (1.f / DIMC) - mu * mu;
  float r = rsqrtf(var + 1e-5f);
  unsigned short* dst = out + (size_t)token * DIMC;
#pragma unroll
  for (int i = 0; i < 6; i++) {
    int c = lane + 64 * i;
    dst[c] = f2bf((v[i] - mu) * r * gamma[c] + beta[c]);
  }
}

// --------------------------- bf16 MFMA GEMM (round-5 staging) --------------
template <bool GELU_ACT, bool ADD_SRC, bool OUT_BF16>
__global__ __launch_bounds__(256) void gemm_bf16_kernel(
    const unsigned short* __restrict__ A, const unsigned short* __restrict__ Bt,
    const float* __restrict__ bias, const float* __restrict__ addsrc,
    void* __restrict__ C, int M, int N, int K) {
  __shared__ unsigned short As[128][72];   // 64 + 8 pad
  __shared__ unsigned short Bs[128][72];
  int tid = threadIdx.x;
  int lane = tid & 63, wid = tid >> 6;
  int wm = wid >> 1, wn = wid & 1;
  int bm0 = blockIdx.x * 128, bn0 = blockIdx.y * 128;

  f32x4 acc[4][4];
#pragma unroll
  for (int m = 0; m < 4; m++)
#pragma unroll
    for (int n = 0; n < 4; n++) acc[m][n] = (f32x4){0.f, 0.f, 0.f, 0.f};

  const unsigned short* Ab = A + (size_t)bm0 * K;
  const unsigned short* Bb = Bt + (size_t)bn0 * K;

  for (int k0 = 0; k0 < K; k0 += 64) {
#pragma unroll
    for (int it = 0; it < 4; it++) {
      int idx = tid + it * 256;
      int row = idx >> 3, seg = idx & 7;
      *(ushort8_t*)&As[row][seg * 8] =
          *(const ushort8_t*)(Ab + (size_t)row * K + k0 + seg * 8);
      *(ushort8_t*)&Bs[row][seg * 8] =
          *(const ushort8_t*)(Bb + (size_t)row * K + k0 + seg * 8);
    }
    __syncthreads();
#pragma unroll
    for (int kk = 0; kk < 2; kk++) {
      bf16x8 af[4], bfr[4];
      int kof = kk * 32 + (lane >> 4) * 8;
#pragma unroll
      for (int m = 0; m < 4; m++)
        af[m] = *(const bf16x8*)&As[wm * 64 + m * 16 + (lane & 15)][kof];
#pragma unroll
      for (int n = 0; n < 4; n++)
        bfr[n] = *(const bf16x8*)&Bs[wn * 64 + n * 16 + (lane & 15)][kof];
#pragma unroll
      for (int m = 0; m < 4; m++)
#pragma unroll
        for (int n = 0; n < 4; n++)
          acc[m][n] = __builtin_amdgcn_mfma_f32_16x16x32_bf16(
              af[m], bfr[n], acc[m][n], 0, 0, 0);
    }
    __syncthreads();
  }

#pragma unroll
  for (int n = 0; n < 4; n++) {
    int col = bn0 + wn * 64 + n * 16 + (lane & 15);
    float bb = bias[col];
#pragma unroll
    for (int m = 0; m < 4; m++) {
      int rowb = bm0 + wm * 64 + m * 16 + ((lane >> 4) << 2);
#pragma unroll
      for (int i = 0; i < 4; i++) {
        float v = acc[m][n][i] + bb;
        if (GELU_ACT) v = 0.5f * v * (1.f + erff(v * 0.70710678118f));
        size_t off = (size_t)(rowb + i) * N + col;
        if (ADD_SRC) v += addsrc[off];
        if (OUT_BF16) ((unsigned short*)C)[off] = f2bf(v);
        else          ((float*)C)[off] = v;
      }
    }
  }
}

// --------------------------- K3: MFMA attention ----------------------------
// One wave per (window, head). 64-padded tiles, 16x16x32 bf16 MFMA.
// S' = mfma(K, Q)  (swapped)  -> D: col(lane&15)=q-token, row=k-token.
// Softmax rows live across lanes sharing lane&15: 2 shfl_xor (16,32).
// P, V^T staged in per-wave LDS with XOR swizzle (slot ^= row&7).
__global__ __launch_bounds__(256) void attn_mfma_kernel(
    const unsigned short* __restrict__ qkv,   // chunk-local [rows][1152] bf16
    const float* __restrict__ combined,       // [4][12][64][64]
    unsigned short* __restrict__ ctx,         // global windowed [TOK][384]
    int wbase) {
  __shared__ unsigned short Plds[4][64][64];
  __shared__ unsigned short Vt[4][32][64];
  __shared__ float rowsum[4][64];

  int wid = threadIdx.x >> 6, lane = threadIdx.x & 63;
  int gi = blockIdx.x * 4 + wid;              // (window-local, head)
  int wl = gi / HEADS;
  int h  = gi % HEADS;
  int wg = wbase + wl;
  int w64 = wg & 63;
  int cls = (((w64 >> 3) == 7) ? 2 : 0) | (((w64 & 7) == 7) ? 1 : 0);
  const float* cmb = combined + ((size_t)(cls * HEADS + h) << 12);

  int q = lane & 15, g = lane >> 4;
  const unsigned short* base = qkv + (size_t)wl * NTOK * (3 * DIMC);
  const unsigned short* Qb = base + h * HDIM;
  const unsigned short* Kb = base + DIMC + h * HDIM;
  const unsigned short* Vb = base + 2 * DIMC + h * HDIM;

  unsigned short* pl = &Plds[wid][0][0];
  unsigned short* vt = &Vt[wid][0][0];

  // ---- stage V^T into LDS (swizzled) ----
  {
    const unsigned short* vr = Vb + (size_t)lane * (3 * DIMC);
    ushort8_t vv[4];
#pragma unroll
    for (int j = 0; j < 4; j++) vv[j] = *(const ushort8_t*)(vr + j * 8);
#pragma unroll
    for (int j = 0; j < 4; j++)
#pragma unroll
      for (int e = 0; e < 8; e++) {
        int d = j * 8 + e;
        vt[d * 64 + (((lane >> 3) ^ (d & 7)) << 3) + (lane & 7)] = vv[j][e];
      }
  }

  // ---- K fragments (A-operand): row = lane&15, k-chunk = g*8 ----
  bf16x8 kf[4];
#pragma unroll
  for (int mi = 0; mi < 4; mi++)
    kf[mi] = *(const bf16x8*)(Kb + (size_t)(16 * mi + q) * (3 * DIMC) + g * 8);

  // ---- QK^T + softmax, one q-block (nj) at a time ----
  const f32x4 zero4 = (f32x4){0.f, 0.f, 0.f, 0.f};
#pragma unroll
  for (int nj = 0; nj < 4; nj++) {
    bf16x8 qf = *(const bf16x8*)(Qb + (size_t)(16 * nj + q) * (3 * DIMC) + g * 8);
    f32x4 sa[4];
#pragma unroll
    for (int mi = 0; mi < 4; mi++)
      sa[mi] = __builtin_amdgcn_mfma_f32_16x16x32_bf16(kf[mi], qf, zero4, 0, 0, 0);
    int qt = 16 * nj + q;
    const float* cr = cmb + qt * 64;
    float mx = -1e30f;
#pragma unroll
    for (int mi = 0; mi < 4; mi++) {
      float4 bb = *(const float4*)&cr[16 * mi + 4 * g];
      sa[mi][0] = sa[mi][0] * QKSCALE + bb.x;
      sa[mi][1] = sa[mi][1] * QKSCALE + bb.y;
      sa[mi][2] = sa[mi][2] * QKSCALE + bb.z;
      sa[mi][3] = sa[mi][3] * QKSCALE + bb.w;
      mx = fmaxf(mx, fmaxf(fmaxf(sa[mi][0], sa[mi][1]), fmaxf(sa[mi][2], sa[mi][3])));
    }
    mx = fmaxf(mx, __shfl_xor(mx, 16, 64));
    mx = fmaxf(mx, __shfl_xor(mx, 32, 64));
    float sm = 0.f;
#pragma unroll
    for (int mi = 0; mi < 4; mi++)
#pragma unroll
      for (int i = 0; i < 4; i++) {
        float p = __expf(sa[mi][i] - mx);
        sa[mi][i] = p; sm += p;
      }
    sm += __shfl_xor(sm, 16, 64);
    sm += __shfl_xor(sm, 32, 64);
    if (g == 0) rowsum[wid][qt] = sm;
    // pack 4 bf16 (kt..kt+3) and write one b64 per mi
#pragma unroll
    for (int mi = 0; mi < 4; mi++) {
      int kt = 16 * mi + 4 * g;
      unsigned int lo = (unsigned int)f2bf(sa[mi][0]) | ((unsigned int)f2bf(sa[mi][1]) << 16);
      unsigned int hi = (unsigned int)f2bf(sa[mi][2]) | ((unsigned int)f2bf(sa[mi][3]) << 16);
      int idx = qt * 64 + (((kt >> 3) ^ (qt & 7)) << 3) + (kt & 7);
      uint2 pk; pk.x = lo; pk.y = hi;
      *(uint2*)&pl[idx] = pk;
    }
  }

  // ---- O = P @ V ----
  f32x4 pacc[4][2];
#pragma unroll
  for (int mi = 0; mi < 4; mi++)
#pragma unroll
    for (int nd = 0; nd < 2; nd++) pacc[mi][nd] = zero4;
#pragma unroll
  for (int kb = 0; kb < 2; kb++) {
    bf16x8 a[4], vfr[2];
#pragma unroll
    for (int mi = 0; mi < 4; mi++) {
      int row = 16 * mi + q;
      a[mi] = *(const bf16x8*)&pl[row * 64 + (((4 * kb + g) ^ (row & 7)) << 3)];
    }
#pragma unroll
    for (int nd = 0; nd < 2; nd++) {
      int row = 16 * nd + q;
      vfr[nd] = *(const bf16x8*)&vt[row * 64 + (((4 * kb + g) ^ (row & 7)) << 3)];
    }
#pragma unroll
    for (int mi = 0; mi < 4; mi++)
#pragma unroll
      for (int nd = 0; nd < 2; nd++)
        pacc[mi][nd] = __builtin_amdgcn_mfma_f32_16x16x32_bf16(
            a[mi], vfr[nd], pacc[mi][nd], 0, 0, 0);
  }

  // ---- normalize + store (rows qt<49 only) ----
#pragma unroll
  for (int mi = 0; mi < 4; mi++)
#pragma unroll
    for (int i = 0; i < 4; i++) {
      int qt = 16 * mi + 4 * g + i;
      if (qt < NTOK) {
        float inv = 1.f / rowsum[wid][qt];
        size_t rowoff = ((size_t)wg * NTOK + qt) * DIMC + h * HDIM;
#pragma unroll
        for (int nd = 0; nd < 2; nd++)
          ctx[rowoff + 16 * nd + q] = f2bf(pacc[mi][nd][i] * inv);
      }
    }
}

// --------------------------- K5: unshift + residual + LN2 ------------------
__global__ __launch_bounds__(256) void unshift_ln2_kernel(
    const float* __restrict__ x, const unsigned short* __restrict__ projw,
    const float* __restrict__ gamma, const float* __restrict__ beta,
    float* __restrict__ hout, unsigned short* __restrict__ ln2) {
  int wave = threadIdx.x >> 6, lane = threadIdx.x & 63;
  int token = blockIdx.x * 4 + wave;
  if (token >= TOK) return;
  int b = token / (HH * WW2);
  int yx = token % (HH * WW2);
  int y = yx / WW2, xq = yx % WW2;
  int ys = y - SHIFTS;  if (ys < 0) ys += HH;
  int xs = xq - SHIFTS; if (xs < 0) xs += WW2;
  int wtok = (b * NW + (ys / WSZ) * 8 + (xs / WSZ)) * NTOK + (ys % WSZ) * WSZ + (xs % WSZ);
  const float* xp = x + (size_t)token * DIMC;
  const unsigned short* pp = projw + (size_t)wtok * DIMC;
  float v[6], s = 0.f, s2 = 0.f;
#pragma unroll
  for (int i = 0; i < 6; i++) {
    int c = lane + 64 * i;
    float hv = xp[c] + bf2f(pp[c]);
    v[i] = hv; s += hv; s2 += hv * hv;
  }
  s = wave_sum(s); s2 = wave_sum(s2);
  float mu = s * (1.f / DIMC);
  float var = s2 * (1.f / DIMC) - mu * mu;
  float r = rsqrtf(var + 1e-5f);
  float* hp = hout + (size_t)token * DIMC;
  unsigned short* lp = ln2 + (size_t)token * DIMC;
#pragma unroll
  for (int i = 0; i < 6; i++) {
    int c = lane + 64 * i;
    hp[c] = v[i];
    lp[c] = f2bf((v[i] - mu) * r * gamma[c] + beta[c]);
  }
}

// --------------------------- launch ----------------------------------------
extern "C" void kernel_launch(void* const* d_in, const int* in_sizes, int n_in,
                              void* d_out, int out_size, void* d_ws, size_t ws_size,
                              hipStream_t stream) {
  const float* x      = (const float*)d_in[0];
  const float* gamma1 = (const float*)d_in[1];
  const float* beta1  = (const float*)d_in[2];
  const float* w_qkv  = (const float*)d_in[3];
  const float* b_qkv  = (const float*)d_in[4];
  const float* rel_t  = (const float*)d_in[5];
  const float* w_proj = (const float*)d_in[6];
  const float* b_proj = (const float*)d_in[7];
  const float* gamma2 = (const float*)d_in[8];
  const float* beta2  = (const float*)d_in[9];
  const float* w_fc1  = (const float*)d_in[10];
  const float* b_fc1  = (const float*)d_in[11];
  const float* w_fc2  = (const float*)d_in[12];
  const float* b_fc2  = (const float*)d_in[13];

  char* p = (char*)d_ws;
  unsigned short* wqkvT = (unsigned short*)p; p += (size_t)1152 * 384 * 2;
  unsigned short* wprojT = (unsigned short*)p; p += (size_t)384 * 384 * 2;
  unsigned short* wfc1T = (unsigned short*)p; p += (size_t)1536 * 384 * 2;
  unsigned short* wfc2T = (unsigned short*)p; p += (size_t)384 * 1536 * 2;
  float* combined = (float*)p; p += (size_t)4 * 12 * 64 * 64 * 4;
  unsigned short* buf1 = (unsigned short*)p; p += (size_t)TOK * DIMC * 2;
  unsigned short* buf2 = (unsigned short*)p; p += (size_t)TOK * DIMC * 2;
  unsigned short* buf3 = (unsigned short*)p; p += (size_t)TOK * DIMC * 2;
  unsigned short* buf4 = (unsigned short*)p;   // chunk scratch (bf16)
  float* out = (float*)d_out;

  transpose_cvt_kernel<<<dim3(384 / 32, 1152 / 32), 256, 0, stream>>>(w_qkv, wqkvT, 384, 1152);
  transpose_cvt_kernel<<<dim3(384 / 32, 384 / 32), 256, 0, stream>>>(w_proj, wprojT, 384, 384);
  transpose_cvt_kernel<<<dim3(384 / 32, 1536 / 32), 256, 0, stream>>>(w_fc1, wfc1T, 384, 1536);
  transpose_cvt_kernel<<<dim3(1536 / 32, 384 / 32), 256, 0, stream>>>(w_fc2, wfc2T, 1536, 384);
  bias_precompute_kernel<<<768, 256, 0, stream>>>(rel_t, combined);

  ln1_window_kernel<<<TOK / 4, 256, 0, stream>>>(x, gamma1, beta1, buf1);

  for (int c = 0; c < NCHUNK; c++) {
    const unsigned short* in = buf1 + (size_t)c * ROWS_PER_CHUNK * DIMC;
    gemm_bf16_kernel<false, false, true>
        <<<dim3(ROWS_PER_CHUNK / 128, 1152 / 128), 256, 0, stream>>>(
        in, wqkvT, b_qkv, nullptr, buf4, ROWS_PER_CHUNK, 3 * DIMC, DIMC);
    attn_mfma_kernel<<<WIN_PER_CHUNK * HEADS / 4, 256, 0, stream>>>(
        buf4, combined, buf2, c * WIN_PER_CHUNK);
  }

  gemm_bf16_kernel<false, false, true>
      <<<dim3(TOK / 128, DIMC / 128), 256, 0, stream>>>(
      buf2, wprojT, b_proj, nullptr, buf3, TOK, DIMC, DIMC);

  unshift_ln2_kernel<<<TOK / 4, 256, 0, stream>>>(x, buf3, gamma2, beta2, out, buf1);

  for (int c = 0; c < NCHUNK; c++) {
    const unsigned short* in = buf1 + (size_t)c * ROWS_PER_CHUNK * DIMC;
    float* hrow = out + (size_t)c * ROWS_PER_CHUNK * DIMC;
    gemm_bf16_kernel<true, false, true>
        <<<dim3(ROWS_PER_CHUNK / 128, HID / 128), 256, 0, stream>>>(
        in, wfc1T, b_fc1, nullptr, buf4, ROWS_PER_CHUNK, HID, DIMC);
    gemm_bf16_kernel<false, true, false>
        <<<dim3(ROWS_PER_CHUNK / 128, DIMC / 128), 256, 0, stream>>>(
        buf4, wfc2T, b_fc2, hrow, hrow, ROWS_PER_CHUNK, DIMC, HID);
  }
}

// Round 8
// 1186.479 us; speedup vs baseline: 1.5482x; 1.1178x over previous
//
#include <hip/hip_runtime.h>

// ---------------------------------------------------------------------------
// Swin block, round 8: GEMM K-loop software-pipelined (2-phase reg prefetch:
// issue tile t+1 global loads after barrier, consume at next ds_write —
// compute phase hides HBM latency). NCHUNK 4 -> 2 (fewer launches, bigger
// grids). Attention/epilogue structure unchanged from round 7.
//  T    transpose+cvt weights
//  B    bias+mask precompute    rel_table   -> combined[4][12][64][64] f32
//  K1   ln1+shift+window        x           -> buf1 (bf16 windowed)
//  K2   qkv gemm (x2, bf16 out) buf1 chunk  -> buf4 (bf16 chunk x 1152)
//  K3   attn mfma (x2)          buf4        -> buf2 (bf16 ctx)
//  K4   proj gemm (bf16 out)    buf2        -> buf3 (bf16)
//  K5   unshift+res+LN2         x, buf3     -> d_out (f32), buf1 (bf16)
//  K6   fc1 gemm+GELU (x2)      buf1 chunk  -> buf4 (bf16 chunk x 1536)
//  K7   fc2 gemm+res (x2)       buf4, d_out -> d_out
// ---------------------------------------------------------------------------

#define DIMC   384
#define HEADS  12
#define HDIM   32
#define WSZ    7
#define SHIFTS 3
#define NTOK   49
#define HID    1536
#define BATCH  32
#define HH     56
#define WW2    56
#define NW     64
#define NWIN   (BATCH*NW)   // 2048
#define TOK    (NWIN*NTOK)  // 100352
#define QKSCALE 0.17677669529663687f

#define NCHUNK 2
#define ROWS_PER_CHUNK (TOK/NCHUNK)     // 50176
#define WIN_PER_CHUNK  (NWIN/NCHUNK)    // 1024

typedef short bf16x8 __attribute__((ext_vector_type(8)));
typedef float f32x4 __attribute__((ext_vector_type(4)));
typedef unsigned short ushort8_t __attribute__((ext_vector_type(8)));

__device__ __forceinline__ unsigned short f2bf(float f) {
  unsigned int u = __builtin_bit_cast(unsigned int, f);
  u += 0x7fffu + ((u >> 16) & 1u);
  return (unsigned short)(u >> 16);
}
__device__ __forceinline__ float bf2f(unsigned short s) {
  unsigned int u = ((unsigned int)s) << 16;
  return __builtin_bit_cast(float, u);
}

__device__ __forceinline__ float wave_sum(float v) {
#pragma unroll
  for (int o = 32; o > 0; o >>= 1) v += __shfl_xor(v, o, 64);
  return v;
}

// --------------------------- weight transpose + bf16 cvt -------------------
__global__ __launch_bounds__(256) void transpose_cvt_kernel(
    const float* __restrict__ W, unsigned short* __restrict__ Wt, int K, int N) {
  __shared__ float t[32][33];
  int k0 = blockIdx.x * 32, n0 = blockIdx.y * 32;
  int tx = threadIdx.x & 31, ty = threadIdx.x >> 5;
#pragma unroll
  for (int i = 0; i < 4; i++) {
    int k = ty + i * 8;
    t[k][tx] = W[(size_t)(k0 + k) * N + n0 + tx];
  }
  __syncthreads();
#pragma unroll
  for (int i = 0; i < 4; i++) {
    int n = ty + i * 8;
    Wt[(size_t)(n0 + n) * K + k0 + tx] = f2bf(t[tx][n]);
  }
}

// --------------------------- bias+mask precompute --------------------------
__global__ __launch_bounds__(256) void bias_precompute_kernel(
    const float* __restrict__ rel, float* __restrict__ combined) {
  int idx = blockIdx.x * 256 + threadIdx.x;      // 4*12*64*64 = 196608
  int kt = idx & 63, qt = (idx >> 6) & 63;
  int hc = idx >> 12;
  int h = hc % 12, cls = hc / 12;
  float v;
  if (kt >= NTOK) v = -30000.f;
  else if (qt >= NTOK) v = 0.f;
  else {
    int yq = qt / 7, xq = qt % 7, yk = kt / 7, xk = kt % 7;
    v = rel[((yq - yk + 6) * 13 + (xq - xk + 6)) * HEADS + h];
    int wy7 = cls >> 1, wx7 = cls & 1;
    int rq = (wy7 ? (yq < 4 ? 1 : 2) : 0) * 3 + (wx7 ? (xq < 4 ? 1 : 2) : 0);
    int rk = (wy7 ? (yk < 4 ? 1 : 2) : 0) * 3 + (wx7 ? (xk < 4 ? 1 : 2) : 0);
    if (rq != rk) v -= 100.f;
  }
  combined[idx] = v;
}

// --------------------------- K1: LN1 + shift + window ----------------------
__global__ __launch_bounds__(256) void ln1_window_kernel(
    const float* __restrict__ x, const float* __restrict__ gamma,
    const float* __restrict__ beta, unsigned short* __restrict__ out) {
  int wave = threadIdx.x >> 6, lane = threadIdx.x & 63;
  int token = blockIdx.x * 4 + wave;
  if (token >= TOK) return;
  int n  = token % NTOK;
  int b_ = token / NTOK;
  int b  = b_ >> 6;
  int w  = b_ & 63;
  int yw = (w >> 3) * WSZ + n / WSZ;
  int xw = (w & 7) * WSZ + n % WSZ;
  int ys = yw + SHIFTS; if (ys >= HH)  ys -= HH;
  int xs = xw + SHIFTS; if (xs >= WW2) xs -= WW2;
  const float* src = x + (size_t)(b * HH * WW2 + ys * WW2 + xs) * DIMC;
  float v[6], s = 0.f, s2 = 0.f;
#pragma unroll
  for (int i = 0; i < 6; i++) {
    v[i] = src[lane + 64 * i];
    s += v[i]; s2 += v[i] * v[i];
  }
  s = wave_sum(s); s2 = wave_sum(s2);
  float mu = s * (1.f / DIMC);
  float var = s2 * (1.f / DIMC) - mu * mu;
  float r = rsqrtf(var + 1e-5f);
  unsigned short* dst = out + (size_t)token * DIMC;
#pragma unroll
  for (int i = 0; i < 6; i++) {
    int c = lane + 64 * i;
    dst[c] = f2bf((v[i] - mu) * r * gamma[c] + beta[c]);
  }
}

// --------------------------- bf16 MFMA GEMM, 2-phase pipelined -------------
// C[M,N] = act(A[M,K]bf16 @ Bt[N,K]bf16^T + bias) (+addsrc). 128x128 tile,
// BK=64, 4 waves, 4x4 16x16x32 frags/wave. Tile t+1 global loads issued
// right after the post-write barrier; consumed at next iteration's ds_write
// -> compute phase hides the load latency.
template <bool GELU_ACT, bool ADD_SRC, bool OUT_BF16>
__global__ __launch_bounds__(256) void gemm_bf16_kernel(
    const unsigned short* __restrict__ A, const unsigned short* __restrict__ Bt,
    const float* __restrict__ bias, const float* __restrict__ addsrc,
    void* __restrict__ C, int M, int N, int K) {
  __shared__ unsigned short As[128][72];   // 64 + 8 pad
  __shared__ unsigned short Bs[128][72];
  int tid = threadIdx.x;
  int lane = tid & 63, wid = tid >> 6;
  int wm = wid >> 1, wn = wid & 1;
  int bm0 = blockIdx.x * 128, bn0 = blockIdx.y * 128;

  f32x4 acc[4][4];
#pragma unroll
  for (int m = 0; m < 4; m++)
#pragma unroll
    for (int n = 0; n < 4; n++) acc[m][n] = (f32x4){0.f, 0.f, 0.f, 0.f};

  const unsigned short* Ab = A + (size_t)bm0 * K;
  const unsigned short* Bb = Bt + (size_t)bn0 * K;

  // per-thread staging coords (4 slots x 16B per matrix)
  ushort8_t ra[4], rb[4];
#pragma unroll
  for (int it = 0; it < 4; it++) {
    int idx = tid + it * 256;
    int row = idx >> 3, seg = idx & 7;
    ra[it] = *(const ushort8_t*)(Ab + (size_t)row * K + seg * 8);
    rb[it] = *(const ushort8_t*)(Bb + (size_t)row * K + seg * 8);
  }

  for (int k0 = 0; k0 < K; k0 += 64) {
    // write staged regs -> LDS
#pragma unroll
    for (int it = 0; it < 4; it++) {
      int idx = tid + it * 256;
      int row = idx >> 3, seg = idx & 7;
      *(ushort8_t*)&As[row][seg * 8] = ra[it];
      *(ushort8_t*)&Bs[row][seg * 8] = rb[it];
    }
    __syncthreads();
    // prefetch tile t+1 into regs (latency hidden by compute below)
    if (k0 + 64 < K) {
#pragma unroll
      for (int it = 0; it < 4; it++) {
        int idx = tid + it * 256;
        int row = idx >> 3, seg = idx & 7;
        ra[it] = *(const ushort8_t*)(Ab + (size_t)row * K + (k0 + 64) + seg * 8);
        rb[it] = *(const ushort8_t*)(Bb + (size_t)row * K + (k0 + 64) + seg * 8);
      }
    }
    // compute from LDS
#pragma unroll
    for (int kk = 0; kk < 2; kk++) {
      bf16x8 af[4], bfr[4];
      int kof = kk * 32 + (lane >> 4) * 8;
#pragma unroll
      for (int m = 0; m < 4; m++)
        af[m] = *(const bf16x8*)&As[wm * 64 + m * 16 + (lane & 15)][kof];
#pragma unroll
      for (int n = 0; n < 4; n++)
        bfr[n] = *(const bf16x8*)&Bs[wn * 64 + n * 16 + (lane & 15)][kof];
#pragma unroll
      for (int m = 0; m < 4; m++)
#pragma unroll
        for (int n = 0; n < 4; n++)
          acc[m][n] = __builtin_amdgcn_mfma_f32_16x16x32_bf16(
              af[m], bfr[n], acc[m][n], 0, 0, 0);
    }
    __syncthreads();
  }

#pragma unroll
  for (int n = 0; n < 4; n++) {
    int col = bn0 + wn * 64 + n * 16 + (lane & 15);
    float bb = bias[col];
#pragma unroll
    for (int m = 0; m < 4; m++) {
      int rowb = bm0 + wm * 64 + m * 16 + ((lane >> 4) << 2);
#pragma unroll
      for (int i = 0; i < 4; i++) {
        float v = acc[m][n][i] + bb;
        if (GELU_ACT) v = 0.5f * v * (1.f + erff(v * 0.70710678118f));
        size_t off = (size_t)(rowb + i) * N + col;
        if (ADD_SRC) v += addsrc[off];
        if (OUT_BF16) ((unsigned short*)C)[off] = f2bf(v);
        else          ((float*)C)[off] = v;
      }
    }
  }
}

// --------------------------- K3: MFMA attention ----------------------------
__global__ __launch_bounds__(256) void attn_mfma_kernel(
    const unsigned short* __restrict__ qkv,   // chunk-local [rows][1152] bf16
    const float* __restrict__ combined,       // [4][12][64][64]
    unsigned short* __restrict__ ctx,         // global windowed [TOK][384]
    int wbase) {
  __shared__ unsigned short Plds[4][64][64];
  __shared__ unsigned short Vt[4][32][64];
  __shared__ float rowsum[4][64];

  int wid = threadIdx.x >> 6, lane = threadIdx.x & 63;
  int gi = blockIdx.x * 4 + wid;
  int wl = gi / HEADS;
  int h  = gi % HEADS;
  int wg = wbase + wl;
  int w64 = wg & 63;
  int cls = (((w64 >> 3) == 7) ? 2 : 0) | (((w64 & 7) == 7) ? 1 : 0);
  const float* cmb = combined + ((size_t)(cls * HEADS + h) << 12);

  int q = lane & 15, g = lane >> 4;
  const unsigned short* base = qkv + (size_t)wl * NTOK * (3 * DIMC);
  const unsigned short* Qb = base + h * HDIM;
  const unsigned short* Kb = base + DIMC + h * HDIM;
  const unsigned short* Vb = base + 2 * DIMC + h * HDIM;

  unsigned short* pl = &Plds[wid][0][0];
  unsigned short* vt = &Vt[wid][0][0];

  // ---- stage V^T into LDS (swizzled) ----
  {
    const unsigned short* vr = Vb + (size_t)lane * (3 * DIMC);
    ushort8_t vv[4];
#pragma unroll
    for (int j = 0; j < 4; j++) vv[j] = *(const ushort8_t*)(vr + j * 8);
#pragma unroll
    for (int j = 0; j < 4; j++)
#pragma unroll
      for (int e = 0; e < 8; e++) {
        int d = j * 8 + e;
        vt[d * 64 + (((lane >> 3) ^ (d & 7)) << 3) + (lane & 7)] = vv[j][e];
      }
  }

  bf16x8 kf[4];
#pragma unroll
  for (int mi = 0; mi < 4; mi++)
    kf[mi] = *(const bf16x8*)(Kb + (size_t)(16 * mi + q) * (3 * DIMC) + g * 8);

  const f32x4 zero4 = (f32x4){0.f, 0.f, 0.f, 0.f};
#pragma unroll
  for (int nj = 0; nj < 4; nj++) {
    bf16x8 qf = *(const bf16x8*)(Qb + (size_t)(16 * nj + q) * (3 * DIMC) + g * 8);
    f32x4 sa[4];
#pragma unroll
    for (int mi = 0; mi < 4; mi++)
      sa[mi] = __builtin_amdgcn_mfma_f32_16x16x32_bf16(kf[mi], qf, zero4, 0, 0, 0);
    int qt = 16 * nj + q;
    const float* cr = cmb + qt * 64;
    float mx = -1e30f;
#pragma unroll
    for (int mi = 0; mi < 4; mi++) {
      float4 bb = *(const float4*)&cr[16 * mi + 4 * g];
      sa[mi][0] = sa[mi][0] * QKSCALE + bb.x;
      sa[mi][1] = sa[mi][1] * QKSCALE + bb.y;
      sa[mi][2] = sa[mi][2] * QKSCALE + bb.z;
      sa[mi][3] = sa[mi][3] * QKSCALE + bb.w;
      mx = fmaxf(mx, fmaxf(fmaxf(sa[mi][0], sa[mi][1]), fmaxf(sa[mi][2], sa[mi][3])));
    }
    mx = fmaxf(mx, __shfl_xor(mx, 16, 64));
    mx = fmaxf(mx, __shfl_xor(mx, 32, 64));
    float sm = 0.f;
#pragma unroll
    for (int mi = 0; mi < 4; mi++)
#pragma unroll
      for (int i = 0; i < 4; i++) {
        float p = __expf(sa[mi][i] - mx);
        sa[mi][i] = p; sm += p;
      }
    sm += __shfl_xor(sm, 16, 64);
    sm += __shfl_xor(sm, 32, 64);
    if (g == 0) rowsum[wid][qt] = sm;
#pragma unroll
    for (int mi = 0; mi < 4; mi++) {
      int kt = 16 * mi + 4 * g;
      unsigned int lo = (unsigned int)f2bf(sa[mi][0]) | ((unsigned int)f2bf(sa[mi][1]) << 16);
      unsigned int hi = (unsigned int)f2bf(sa[mi][2]) | ((unsigned int)f2bf(sa[mi][3]) << 16);
      int idx = qt * 64 + (((kt >> 3) ^ (qt & 7)) << 3) + (kt & 7);
      uint2 pk; pk.x = lo; pk.y = hi;
      *(uint2*)&pl[idx] = pk;
    }
  }

  f32x4 pacc[4][2];
#pragma unroll
  for (int mi = 0; mi < 4; mi++)
#pragma unroll
    for (int nd = 0; nd < 2; nd++) pacc[mi][nd] = zero4;
#pragma unroll
  for (int kb = 0; kb < 2; kb++) {
    bf16x8 a[4], vfr[2];
#pragma unroll
    for (int mi = 0; mi < 4; mi++) {
      int row = 16 * mi + q;
      a[mi] = *(const bf16x8*)&pl[row * 64 + (((4 * kb + g) ^ (row & 7)) << 3)];
    }
#pragma unroll
    for (int nd = 0; nd < 2; nd++) {
      int row = 16 * nd + q;
      vfr[nd] = *(const bf16x8*)&vt[row * 64 + (((4 * kb + g) ^ (row & 7)) << 3)];
    }
#pragma unroll
    for (int mi = 0; mi < 4; mi++)
#pragma unroll
      for (int nd = 0; nd < 2; nd++)
        pacc[mi][nd] = __builtin_amdgcn_mfma_f32_16x16x32_bf16(
            a[mi], vfr[nd], pacc[mi][nd], 0, 0, 0);
  }

#pragma unroll
  for (int mi = 0; mi < 4; mi++)
#pragma unroll
    for (int i = 0; i < 4; i++) {
      int qt = 16 * mi + 4 * g + i;
      if (qt < NTOK) {
        float inv = 1.f / rowsum[wid][qt];
        size_t rowoff = ((size_t)wg * NTOK + qt) * DIMC + h * HDIM;
#pragma unroll
        for (int nd = 0; nd < 2; nd++)
          ctx[rowoff + 16 * nd + q] = f2bf(pacc[mi][nd][i] * inv);
      }
    }
}

// --------------------------- K5: unshift + residual + LN2 ------------------
__global__ __launch_bounds__(256) void unshift_ln2_kernel(
    const float* __restrict__ x, const unsigned short* __restrict__ projw,
    const float* __restrict__ gamma, const float* __restrict__ beta,
    float* __restrict__ hout, unsigned short* __restrict__ ln2) {
  int wave = threadIdx.x >> 6, lane = threadIdx.x & 63;
  int token = blockIdx.x * 4 + wave;
  if (token >= TOK) return;
  int b = token / (HH * WW2);
  int yx = token % (HH * WW2);
  int y = yx / WW2, xq = yx % WW2;
  int ys = y - SHIFTS;  if (ys < 0) ys += HH;
  int xs = xq - SHIFTS; if (xs < 0) xs += WW2;
  int wtok = (b * NW + (ys / WSZ) * 8 + (xs / WSZ)) * NTOK + (ys % WSZ) * WSZ + (xs % WSZ);
  const float* xp = x + (size_t)token * DIMC;
  const unsigned short* pp = projw + (size_t)wtok * DIMC;
  float v[6], s = 0.f, s2 = 0.f;
#pragma unroll
  for (int i = 0; i < 6; i++) {
    int c = lane + 64 * i;
    float hv = xp[c] + bf2f(pp[c]);
    v[i] = hv; s += hv; s2 += hv * hv;
  }
  s = wave_sum(s); s2 = wave_sum(s2);
  float mu = s * (1.f / DIMC);
  float var = s2 * (1.f / DIMC) - mu * mu;
  float r = rsqrtf(var + 1e-5f);
  float* hp = hout + (size_t)token * DIMC;
  unsigned short* lp = ln2 + (size_t)token * DIMC;
#pragma unroll
  for (int i = 0; i < 6; i++) {
    int c = lane + 64 * i;
    hp[c] = v[i];
    lp[c] = f2bf((v[i] - mu) * r * gamma[c] + beta[c]);
  }
}

// --------------------------- launch ----------------------------------------
extern "C" void kernel_launch(void* const* d_in, const int* in_sizes, int n_in,
                              void* d_out, int out_size, void* d_ws, size_t ws_size,
                              hipStream_t stream) {
  const float* x      = (const float*)d_in[0];
  const float* gamma1 = (const float*)d_in[1];
  const float* beta1  = (const float*)d_in[2];
  const float* w_qkv  = (const float*)d_in[3];
  const float* b_qkv  = (const float*)d_in[4];
  const float* rel_t  = (const float*)d_in[5];
  const float* w_proj = (const float*)d_in[6];
  const float* b_proj = (const float*)d_in[7];
  const float* gamma2 = (const float*)d_in[8];
  const float* beta2  = (const float*)d_in[9];
  const float* w_fc1  = (const float*)d_in[10];
  const float* b_fc1  = (const float*)d_in[11];
  const float* w_fc2  = (const float*)d_in[12];
  const float* b_fc2  = (const float*)d_in[13];

  char* p = (char*)d_ws;
  unsigned short* wqkvT = (unsigned short*)p; p += (size_t)1152 * 384 * 2;
  unsigned short* wprojT = (unsigned short*)p; p += (size_t)384 * 384 * 2;
  unsigned short* wfc1T = (unsigned short*)p; p += (size_t)1536 * 384 * 2;
  unsigned short* wfc2T = (unsigned short*)p; p += (size_t)384 * 1536 * 2;
  float* combined = (float*)p; p += (size_t)4 * 12 * 64 * 64 * 4;
  unsigned short* buf1 = (unsigned short*)p; p += (size_t)TOK * DIMC * 2;
  unsigned short* buf2 = (unsigned short*)p; p += (size_t)TOK * DIMC * 2;
  unsigned short* buf3 = (unsigned short*)p; p += (size_t)TOK * DIMC * 2;
  unsigned short* buf4 = (unsigned short*)p;   // chunk scratch (bf16), 154 MB max
  float* out = (float*)d_out;

  transpose_cvt_kernel<<<dim3(384 / 32, 1152 / 32), 256, 0, stream>>>(w_qkv, wqkvT, 384, 1152);
  transpose_cvt_kernel<<<dim3(384 / 32, 384 / 32), 256, 0, stream>>>(w_proj, wprojT, 384, 384);
  transpose_cvt_kernel<<<dim3(384 / 32, 1536 / 32), 256, 0, stream>>>(w_fc1, wfc1T, 384, 1536);
  transpose_cvt_kernel<<<dim3(1536 / 32, 384 / 32), 256, 0, stream>>>(w_fc2, wfc2T, 1536, 384);
  bias_precompute_kernel<<<768, 256, 0, stream>>>(rel_t, combined);

  ln1_window_kernel<<<TOK / 4, 256, 0, stream>>>(x, gamma1, beta1, buf1);

  for (int c = 0; c < NCHUNK; c++) {
    const unsigned short* in = buf1 + (size_t)c * ROWS_PER_CHUNK * DIMC;
    gemm_bf16_kernel<false, false, true>
        <<<dim3(ROWS_PER_CHUNK / 128, 1152 / 128), 256, 0, stream>>>(
        in, wqkvT, b_qkv, nullptr, buf4, ROWS_PER_CHUNK, 3 * DIMC, DIMC);
    attn_mfma_kernel<<<WIN_PER_CHUNK * HEADS / 4, 256, 0, stream>>>(
        buf4, combined, buf2, c * WIN_PER_CHUNK);
  }

  gemm_bf16_kernel<false, false, true>
      <<<dim3(TOK / 128, DIMC / 128), 256, 0, stream>>>(
      buf2, wprojT, b_proj, nullptr, buf3, TOK, DIMC, DIMC);

  unshift_ln2_kernel<<<TOK / 4, 256, 0, stream>>>(x, buf3, gamma2, beta2, out, buf1);

  for (int c = 0; c < NCHUNK; c++) {
    const unsigned short* in = buf1 + (size_t)c * ROWS_PER_CHUNK * DIMC;
    float* hrow = out + (size_t)c * ROWS_PER_CHUNK * DIMC;
    gemm_bf16_kernel<true, false, true>
        <<<dim3(ROWS_PER_CHUNK / 128, HID / 128), 256, 0, stream>>>(
        in, wfc1T, b_fc1, nullptr, buf4, ROWS_PER_CHUNK, HID, DIMC);
    gemm_bf16_kernel<false, true, false>
        <<<dim3(ROWS_PER_CHUNK / 128, DIMC / 128), 256, 0, stream>>>(
        buf4, wfc2T, b_fc2, hrow, hrow, ROWS_PER_CHUNK, DIMC, HID);
  }
}